// Round 3
// baseline (413.337 us; speedup 1.0000x reference)
//
#include <hip/hip_runtime.h>

// CXTRNN: T=512 serial steps, B=4096 chains, HID=50, RANK=6.
// share_io collapses z-einsums: inp = zsum*(W_in@s+b_in); out = zsum*(W_out@tanh(x)+b_out).
//
// R3 layout: 32 lanes per batch element -> 4096*32/64 = 2048 waves = 2 waves/SIMD (TLP!).
// A wave holds 2 b: group0 = rows {0,2} (lanes 0-15,32-47), group1 = rows {1,3}.
// This makes the cross-half step of the 32-lane all-reduce a v_permlane32_swap_b32
// (VALU speed): sum of its two outputs == v[lane] + v[lane^32] on every lane.
// Lane owns HPL=2 h-slots (pad 50->64). g broadcast via ds_swizzle (lane&0x10)|r.

#define SEQ_T 512
#define NB    4096
#define HPL   2

__device__ __forceinline__ float fexp2(float x) { return __builtin_amdgcn_exp2f(x); }
__device__ __forceinline__ float frcpf(float x) { return __builtin_amdgcn_rcpf(x); }
__device__ __forceinline__ float ftanh(float x) {
  return fmaf(-2.f, frcpf(fexp2(2.8853900817779268f * x) + 1.f), 1.f);
}
__device__ __forceinline__ float fsigm(float x) {
  return frcpf(1.f + fexp2(-1.4426950408889634f * x));
}

template <int CTRL>
__device__ __forceinline__ float dpp_add(float v) {
  int p = __builtin_amdgcn_update_dpp(0, __float_as_int(v), CTRL, 0xF, 0xF, true);
  return v + __int_as_float(p);
}

// v[lane] + v[lane^32], all lanes, VALU-speed on gfx950.
__device__ __forceinline__ float add_x32(float v) {
#if defined(__has_builtin)
#if __has_builtin(__builtin_amdgcn_permlane32_swap)
  auto p = __builtin_amdgcn_permlane32_swap(__float_as_uint(v), __float_as_uint(v),
                                            false, false);
  return __uint_as_float(p[0]) + __uint_as_float(p[1]);
#else
  return v + __shfl_xor(v, 32, 64);
#endif
#else
  return v + __shfl_xor(v, 32, 64);
#endif
}

// all-reduce over the 32-lane group {row, row+2}: 4 DPP stages (within 16-row)
// then the permlane cross-half add.
__device__ __forceinline__ float red32(float v) {
  v = dpp_add<0xB1>(v);     // quad_perm xor1
  v = dpp_add<0x4E>(v);     // quad_perm xor2
  v = dpp_add<0x124>(v);    // row_ror:4
  v = dpp_add<0x128>(v);    // row_ror:8  -> row sums
  return add_x32(v);        // rows 0+2 / 1+3
}

__device__ __forceinline__ float swz(float v, int pat);
#define SWZ(v, imm) __int_as_float(__builtin_amdgcn_ds_swizzle(__float_as_int(v), (imm)))

__global__ __launch_bounds__(256) void cxtrnn_kernel(
    const float* __restrict__ S,  const float* __restrict__ Z,
    const float* __restrict__ U,  const float* __restrict__ V,
    const float* __restrict__ Wi, const float* __restrict__ Bi,
    const float* __restrict__ Wo, const float* __restrict__ Bo,
    const float* __restrict__ NW, const float* __restrict__ NBv,
    float* __restrict__ out)
{
  const int tid  = threadIdx.x;
  const int lane = tid & 63;
  const int wid  = tid >> 6;                 // wave in block (0..3)
  const int l16  = lane & 15;
  const int grp  = (lane >> 4) & 1;          // rows 0,2 -> group 0 ; rows 1,3 -> group 1
  const int b    = (blockIdx.x * 4 + wid) * 2 + grp;
  const int hl   = l16 | ((lane >> 5) << 4); // h-slot pair index 0..31

  // ---- weights into registers (zero-padded for h >= 50) ----
  float vw[HPL][6], uw[HPL][6], wiw[HPL][3], biw[HPL], wow[3][HPL];
#pragma unroll
  for (int i = 0; i < HPL; ++i) {
    const int h = hl * HPL + i;
    const bool ok = h < 50;
#pragma unroll
    for (int r = 0; r < 6; ++r) {
      vw[i][r] = ok ? V[h * 6 + r] : 0.f;
      uw[i][r] = ok ? U[h * 6 + r] : 0.f;
    }
#pragma unroll
    for (int c = 0; c < 3; ++c) wiw[i][c] = ok ? Wi[h * 3 + c] : 0.f;
    biw[i] = ok ? Bi[h] : 0.f;
#pragma unroll
    for (int y = 0; y < 3; ++y) wow[y][i] = ok ? Wo[y * 50 + h] : 0.f;
  }
  // every 16-row's lanes 0..5 hold nm_W row r for THEIR group (rows 0,2 = grp0 z's).
  float nw[6], nb;
  {
    const int r = (l16 < 6) ? l16 : 0;
#pragma unroll
    for (int k = 0; k < 6; ++k) nw[k] = NW[r * 6 + k];
    nb = NBv[r];
  }
  const float bo = (l16 < 3) ? Bo[l16] : 0.f;

  float x[HPL]  = {0.f, 0.f};
  float th[HPL] = {0.f, 0.f};

  const float* sp = S + (size_t)b * 3;
  const float* zp = Z + (size_t)b * 6;
  float* op = out + (size_t)b * 3 + (l16 < 3 ? l16 : 0);

  float zsum_c, gc[6], ii_c[HPL];
  auto prep = [&](float s0, float s1, float s2,
                  float z0, float z1, float z2, float z3, float z4, float z5) {
    zsum_c = ((z0 + z1) + (z2 + z3)) + (z4 + z5);
    float ga = nb;
    ga = fmaf(z0, nw[0], ga); ga = fmaf(z1, nw[1], ga);
    ga = fmaf(z2, nw[2], ga); ga = fmaf(z3, nw[3], ga);
    ga = fmaf(z4, nw[4], ga); ga = fmaf(z5, nw[5], ga);
    const float gv = fsigm(ga);
    // broadcast lane ((lane&0x10)|r) of each half -> whole 16-row (group-correct).
    gc[0] = SWZ(gv, 0x010);
    gc[1] = SWZ(gv, 0x030);
    gc[2] = SWZ(gv, 0x050);
    gc[3] = SWZ(gv, 0x070);
    gc[4] = SWZ(gv, 0x090);
    gc[5] = SWZ(gv, 0x0B0);
    const float hz = 0.5f * zsum_c;
#pragma unroll
    for (int i = 0; i < HPL; ++i) {
      float ii = biw[i];
      ii = fmaf(s0, wiw[i][0], ii);
      ii = fmaf(s1, wiw[i][1], ii);
      ii = fmaf(s2, wiw[i][2], ii);
      ii_c[i] = hz * ii;
    }
  };

  // ---- software pipeline fill: load t=0, prep t=0, load t=1 ----
  float lbs0 = sp[0], lbs1 = sp[1], lbs2 = sp[2];
  float lbz0 = zp[0], lbz1 = zp[1], lbz2 = zp[2];
  float lbz3 = zp[3], lbz4 = zp[4], lbz5 = zp[5];
  prep(lbs0, lbs1, lbs2, lbz0, lbz1, lbz2, lbz3, lbz4, lbz5);
  lbs0 = sp[NB * 3 + 0]; lbs1 = sp[NB * 3 + 1]; lbs2 = sp[NB * 3 + 2];
  lbz0 = zp[NB * 6 + 0]; lbz1 = zp[NB * 6 + 1]; lbz2 = zp[NB * 6 + 2];
  lbz3 = zp[NB * 6 + 3]; lbz4 = zp[NB * 6 + 4]; lbz5 = zp[NB * 6 + 5];
  sp += (size_t)2 * NB * 3;
  zp += (size_t)2 * NB * 6;

#pragma unroll 2
  for (int t = 0; t < SEQ_T; ++t) {
    // issue loads for t+2 (consumed by prep one full iteration later)
    float ns0 = 0.f, ns1 = 0.f, ns2 = 0.f;
    float nz0 = 0.f, nz1 = 0.f, nz2 = 0.f, nz3 = 0.f, nz4 = 0.f, nz5 = 0.f;
    if (t + 2 < SEQ_T) {
      ns0 = sp[0]; ns1 = sp[1]; ns2 = sp[2];
      nz0 = zp[0]; nz1 = zp[1]; nz2 = zp[2];
      nz3 = zp[3]; nz4 = zp[4]; nz5 = zp[5];
    }

    // ---- recurrence for step t (critical chain) ----
    float pa[6] = {0.f, 0.f, 0.f, 0.f, 0.f, 0.f};
#pragma unroll
    for (int i = 0; i < HPL; ++i)
#pragma unroll
      for (int r = 0; r < 6; ++r) pa[r] = fmaf(th[i], vw[i][r], pa[r]);
#pragma unroll
    for (int r = 0; r < 6; ++r) pa[r] = red32(pa[r]);
    float ag[6];
#pragma unroll
    for (int r = 0; r < 6; ++r) ag[r] = pa[r] * gc[r];

    float hp[HPL];
#pragma unroll
    for (int i = 0; i < HPL; ++i) hp[i] = fmaf(0.5f, x[i], ii_c[i]);

    float po0 = 0.f, po1 = 0.f, po2 = 0.f;
#pragma unroll
    for (int i = 0; i < HPL; ++i) {
      float tm01 = fmaf(ag[1], uw[i][1], ag[0] * uw[i][0]);
      float tm23 = fmaf(ag[3], uw[i][3], ag[2] * uw[i][2]);
      float tm45 = fmaf(ag[5], uw[i][5], ag[4] * uw[i][4]);
      const float tm = (tm01 + tm23) + tm45;
      const float xn = fmaf(0.5f, tm, hp[i]);
      x[i] = xn;
      const float ty = ftanh(xn);
      th[i] = ty;
      po0 = fmaf(ty, wow[0][i], po0);
      po1 = fmaf(ty, wow[1][i], po1);
      po2 = fmaf(ty, wow[2][i], po2);
    }

    // ---- output for step t (off the recurrence chain) ----
    po0 = red32(po0); po1 = red32(po1); po2 = red32(po2);
    if (lane < 32 && l16 < 3) {
      const float pv = (l16 == 0) ? po0 : (l16 == 1) ? po1 : po2;
      *op = zsum_c * (pv + bo);
    }

    // ---- prepare step t+1 from regs loaded one iteration ago ----
    prep(lbs0, lbs1, lbs2, lbz0, lbz1, lbz2, lbz3, lbz4, lbz5);

    lbs0 = ns0; lbs1 = ns1; lbs2 = ns2;
    lbz0 = nz0; lbz1 = nz1; lbz2 = nz2;
    lbz3 = nz3; lbz4 = nz4; lbz5 = nz5;
    sp += (size_t)NB * 3;
    zp += (size_t)NB * 6;
    op += (size_t)NB * 3;
  }
}

extern "C" void kernel_launch(void* const* d_in, const int* in_sizes, int n_in,
                              void* d_out, int out_size, void* d_ws, size_t ws_size,
                              hipStream_t stream) {
  const float* S   = (const float*)d_in[0];
  const float* Z   = (const float*)d_in[1];
  const float* U   = (const float*)d_in[2];
  const float* V   = (const float*)d_in[3];
  const float* Wi  = (const float*)d_in[4];
  const float* Bi  = (const float*)d_in[5];
  const float* Wo  = (const float*)d_in[6];
  const float* Bo  = (const float*)d_in[7];
  const float* NW  = (const float*)d_in[8];
  const float* NBv = (const float*)d_in[9];
  float* out = (float*)d_out;

  cxtrnn_kernel<<<dim3(512), dim3(256), 0, stream>>>(
      S, Z, U, V, Wi, Bi, Wo, Bo, NW, NBv, out);
}